// Round 13
// baseline (1080.062 us; speedup 1.0000x reference)
//
#include <hip/hip_runtime.h>

#define HH 56
#define WW 56
#define CC 512
#define BB 32
#define LL (HH*WW)
#define MM (BB*LL)     // 100352 tokens
#define HID 2048

typedef __attribute__((ext_vector_type(8))) __bf16 bf16x8;
typedef __attribute__((ext_vector_type(4))) float f32x4;
typedef __attribute__((ext_vector_type(4))) short s16x4;

__device__ __forceinline__ short f2bf(float f) {
    union { float f; unsigned u; } c; c.f = f;
    unsigned r = c.u + 0x7fffu + ((c.u >> 16) & 1u);   // round-to-nearest-even
    return (short)(r >> 16);
}
__device__ __forceinline__ float bf2f(short s) {
    union { unsigned u; float f; } c; c.u = ((unsigned)(unsigned short)s) << 16;
    return c.f;
}

// fast gelu: v * t/(t+1), t = e^{2*0.7978845608*(v+0.044715 v^3)}
__device__ __forceinline__ float gelu_fast(float v) {
    float xg = 0.7978845608f * (v + 0.044715f * v * v * v);
    xg = fminf(xg, 15.0f);
    float t = __expf(2.0f * xg);
    return v * (t / (t + 1.0f));
}

// ---------------- f32 -> bf16 weight conversion ----------------
__global__ __launch_bounds__(256) void cvt_bf16(const float* __restrict__ in,
                                                short* __restrict__ out, int n) {
    int i = blockIdx.x * 256 + threadIdx.x;
    if (i < n) out[i] = f2bf(in[i]);
}

// -------- LayerNorm over 512 channels, 2 rows / block, float4 loads ---------
__global__ __launch_bounds__(256) void ln512v(const float* __restrict__ x,
                                              const float* __restrict__ g,
                                              const float* __restrict__ b,
                                              short* __restrict__ out) {
    const int t = threadIdx.x;
    const int rsel = t >> 7;                       // 0..1 row within block
    const int col = t & 127;                       // float4 column
    const long row = (long)blockIdx.x * 2 + rsel;
    const f32x4 v = ((const f32x4*)(x + row * 512))[col];
    float s = v[0] + v[1] + v[2] + v[3];
    float q = v[0]*v[0] + v[1]*v[1] + v[2]*v[2] + v[3]*v[3];
#pragma unroll
    for (int off = 32; off > 0; off >>= 1) {
        s += __shfl_xor(s, off, 64);
        q += __shfl_xor(q, off, 64);
    }
    __shared__ float red[8];
    const int wv = t >> 6;                         // 0..3 (waves 0,1=row0; 2,3=row1)
    if ((t & 63) == 0) { red[wv] = s; red[4 + wv] = q; }
    __syncthreads();
    s = red[rsel * 2] + red[rsel * 2 + 1];
    q = red[4 + rsel * 2] + red[4 + rsel * 2 + 1];
    const float mu = s * (1.0f / 512.0f);
    const float rs = rsqrtf(q * (1.0f / 512.0f) - mu * mu + 1e-5f);
    const f32x4 gv = ((const f32x4*)g)[col];
    const f32x4 bv = ((const f32x4*)b)[col];
    s16x4 o;
#pragma unroll
    for (int r = 0; r < 4; ++r)
        o[r] = f2bf((v[r] - mu) * rs * gv[r] + bv[r]);
    *(s16x4*)(out + row * 512 + col * 4) = o;
}

// ------- spatial (window) MLP + residual, 2 channels / thread ---------------
__global__ __launch_bounds__(256) void spatial_mlp(const short* __restrict__ xn,
                                                   const float* __restrict__ x,
                                                   const float* __restrict__ sw,
                                                   const float* __restrict__ sb,
                                                   float* x1) {
    const int head = blockIdx.y;
    const int t = threadIdx.x;
    const int chp = t & 15;                       // channel pair 0..15
    const int wloc = t >> 4;                      // 0..15 windows
    const int win = blockIdx.x * 16 + wloc;       // 0..2591
    const int b = win / 81;
    const int rr = win - b * 81;
    const int wi = rr / 9;
    const int wj = rr - wi * 9;
    const int c = head * 32 + chp * 2;

    float2 xv[49];
#pragma unroll
    for (int j = 0; j < 49; j++) {
        const int pr = wi * 7 + j / 7 - 4;        // padded row - P_T
        const int pc = wj * 7 + j % 7 - 4;        // padded col - P_L
        float2 v = {0.0f, 0.0f};
        if (pr >= 0 && pr < 56 && pc >= 0 && pc < 56) {
            const long idx = ((long)((b * 56 + pr) * 56 + pc)) * 512 + c;
            const ushort2 u = *(const ushort2*)(xn + idx);
            v.x = bf2f((short)u.x);
            v.y = bf2f((short)u.y);
        }
        xv[j] = v;
    }

    const float* swh = sw + head * 2401;
    const float* sbh = sb + head * 49;

#pragma unroll 1
    for (int t7 = 0; t7 < 7; t7++) {
        float2 acc[7];
#pragma unroll
        for (int ii = 0; ii < 7; ii++) {
            const float bb = sbh[t7 * 7 + ii];
            acc[ii].x = bb; acc[ii].y = bb;
        }
#pragma unroll
        for (int ii = 0; ii < 7; ii++) {
            const float* swr = swh + (t7 * 7 + ii) * 49;
#pragma unroll
            for (int j = 0; j < 49; j++) {
                acc[ii].x = fmaf(swr[j], xv[j].x, acc[ii].x);
                acc[ii].y = fmaf(swr[j], xv[j].y, acc[ii].y);
            }
        }
        const int pr = wi * 7 + t7 - 4;
        if (pr >= 0 && pr < 56) {
#pragma unroll
            for (int ii = 0; ii < 7; ii++) {
                const int pc = wj * 7 + ii - 4;
                if (pc >= 0 && pc < 56) {
                    const long idx = ((long)((b * 56 + pr) * 56 + pc)) * 512 + c;
                    const float2 rv = *(const float2*)(x + idx);
                    float2 o; o.x = rv.x + acc[ii].x; o.y = rv.y + acc[ii].y;
                    *(float2*)(x1 + idx) = o;
                }
            }
        }
    }
}

// ------- 128x128 4-wave bf16 GEMM, REG-STAGED double buffer ------------------
// r5 geometry/read-path verbatim; staging mechanism swapped (the one-variable
// A/B): global_load_dwordx4 -> named VGPR banks (2-deep) -> ds_write_b128.
// Compiler auto-inserts COUNTED vmcnt before each ds_write (VGPR dep) and
// handles WAR via the lgkmcnt(0). Swizzle applied at ds_write address
// (global loads fully linear). 2 LDS slots = 32 KB, 3 blocks/CU as r5.
// Per K-tile: {issue 4 gloads t+2; 4 ds_write t+1; 8 ds_read t; lgkmcnt(0);
// setprio(1); 16 MFMA; setprio(0); s_barrier}.
template <int K, int N, bool GELU>
__global__ __launch_bounds__(256, 3) void gemmrs(const short* __restrict__ A,
                                                 const short* __restrict__ Bw,
                                                 const float* __restrict__ bias,
                                                 const float* res,
                                                 void* Cout) {
    __shared__ __attribute__((aligned(16))) char S[32768];  // A slots @0,8K; B @16K,24K
    const int tid = threadIdx.x;
    const int lane = tid & 63;
    const int wid = tid >> 6;
    const int wr = wid >> 1;          // 0..1  M-half (64 rows)
    const int wc = wid & 1;           // 0..1  N-half (64 cols)
    const int lr = lane & 15;
    const int kg = (lane >> 4) & 3;

    // T1: bijective XCD-aware remap (nwg % 8 == 0)
    const int gx = gridDim.x;
    const int lin = blockIdx.y * gx + blockIdx.x;
    const int cpx = (gx * gridDim.y) >> 3;
    const int orig = (lin & 7) * cpx + (lin >> 3);
    const long mBase = (long)(orig / gx) * 128;
    const long nBase = (long)(orig % gx) * 128;

    // global sources: LINEAR (swizzle moved to ds_write address)
    const int sRow = tid >> 2;                        // 0..63
    const short* aSrc0 = A + (mBase + sRow) * K + (tid & 3) * 8;
    const short* aSrc1 = A + (mBase + 64 + sRow) * K + (tid & 3) * 8;
    const short* bSrc0 = Bw + (nBase + sRow) * K + (tid & 3) * 8;
    const short* bSrc1 = Bw + (nBase + 64 + sRow) * K + (tid & 3) * 8;

    // ds_write byte offset: row*64 + (chunk ^ key(row))*16, key = (row>>1)&3
    const int wByte = sRow * 64 + (((tid & 3) ^ ((tid >> 3) & 3)) << 4);

    // read-side fragment offsets (r5 verbatim, verified 0-conflict)
    const int swzc = kg ^ ((lr >> 1) & 3);
    const int aOff = (wr * 64 + lr) * 64 + swzc * 16;    // + m*1024, m=0..3
    const int bOff = (wc * 64 + lr) * 64 + swzc * 16;    // + n*1024, n=0..3

    f32x4 acc[4][4] = {};
    const int NT = K / 32;
    static_assert((K / 32) % 2 == 0, "NT even");

    // 2-deep named register banks (rule #20: static names only)
    f32x4 rA00, rA01, rB00, rB01;     // bank 0 (even tiles)
    f32x4 rA10, rA11, rB10, rB11;     // bank 1 (odd tiles)

#define LOADBANK(P, T) do {                                                     \
        const long k0_ = (long)(T) * 32;                                        \
        rA##P##0 = *(const f32x4*)(aSrc0 + k0_);                                \
        rA##P##1 = *(const f32x4*)(aSrc1 + k0_);                                \
        rB##P##0 = *(const f32x4*)(bSrc0 + k0_);                                \
        rB##P##1 = *(const f32x4*)(bSrc1 + k0_);                                \
    } while (0)

#define WRITEBANK(P) do {                                                       \
        *(f32x4*)(S + (P) * 8192 + wByte)          = rA##P##0;                  \
        *(f32x4*)(S + (P) * 8192 + 4096 + wByte)   = rA##P##1;                  \
        *(f32x4*)(S + 16384 + (P) * 8192 + wByte)        = rB##P##0;            \
        *(f32x4*)(S + 16384 + (P) * 8192 + 4096 + wByte) = rB##P##1;            \
    } while (0)

    // BODY(P = t&1, Q = 1-P, T): read slot P, write tile T+1 (bank Q) -> slot Q,
    // issue loads tile T+2 -> bank P.
#define BODY(P, Q, T) do {                                                      \
        if ((T) + 2 < NT) LOADBANK(P, (T) + 2);                                 \
        if ((T) + 1 < NT) WRITEBANK(Q);                                         \
        const char* Ab_ = S + (P) * 8192;                                       \
        const char* Bb_ = S + 16384 + (P) * 8192;                               \
        bf16x8 af[4], bfv[4];                                                   \
        _Pragma("unroll")                                                       \
        for (int m = 0; m < 4; ++m) af[m] = *(const bf16x8*)(Ab_ + aOff + m * 1024); \
        _Pragma("unroll")                                                       \
        for (int n = 0; n < 4; ++n) bfv[n] = *(const bf16x8*)(Bb_ + bOff + n * 1024); \
        asm volatile("s_waitcnt lgkmcnt(0)" ::: "memory");                      \
        __builtin_amdgcn_s_setprio(1);                                          \
        _Pragma("unroll")                                                       \
        for (int m = 0; m < 4; ++m)                                             \
            _Pragma("unroll")                                                   \
            for (int n = 0; n < 4; ++n)                                         \
                acc[m][n] = __builtin_amdgcn_mfma_f32_16x16x32_bf16(bfv[n], af[m], acc[m][n], 0, 0, 0); \
        __builtin_amdgcn_s_setprio(0);                                          \
        __builtin_amdgcn_s_barrier();                                           \
    } while (0)

    // prologue: tile0 -> bank0 -> slot0; tile1 -> bank1 (in regs)
    LOADBANK(0, 0);
    LOADBANK(1, 1);
    WRITEBANK(0);                      // compiler: counted vmcnt before writes
    asm volatile("s_waitcnt lgkmcnt(0)" ::: "memory");
    __builtin_amdgcn_s_barrier();

    for (int t = 0; t < NT; t += 2) {
        BODY(0, 1, t);
        BODY(1, 0, t + 1);
    }
#undef BODY
#undef WRITEBANK
#undef LOADBANK

    // epilogue: operand-swapped fragment = C^T layout:
    //   C row  = mBase + wr*64 + m*16 + lr
    //   C cols = nBase + wc*64 + n*16 + kg*4 + (0..3)   (consecutive)
#pragma unroll
    for (int n = 0; n < 4; ++n) {
        const long col0 = nBase + wc * 64 + n * 16 + kg * 4;
        const f32x4 bv4 = *(const f32x4*)(bias + col0);
#pragma unroll
        for (int m = 0; m < 4; ++m) {
            const long row = mBase + wr * 64 + m * 16 + lr;
            const long idx = row * N + col0;
            if (GELU) {
                s16x4 o;
#pragma unroll
                for (int r = 0; r < 4; ++r)
                    o[r] = f2bf(gelu_fast(acc[m][n][r] + bv4[r]));
                *(s16x4*)((short*)Cout + idx) = o;
            } else {
                const f32x4 rv = *(const f32x4*)(res + idx);
                f32x4 o;
#pragma unroll
                for (int r = 0; r < 4; ++r) o[r] = acc[m][n][r] + bv4[r] + rv[r];
                *(f32x4*)((float*)Cout + idx) = o;
            }
        }
    }
}

extern "C" void kernel_launch(void* const* d_in, const int* in_sizes, int n_in,
                              void* d_out, int out_size, void* d_ws, size_t ws_size,
                              hipStream_t stream) {
    const float* x    = (const float*)d_in[0];
    const float* n1g  = (const float*)d_in[1];
    const float* n1b  = (const float*)d_in[2];
    const float* sw   = (const float*)d_in[3];
    const float* sb   = (const float*)d_in[4];
    const float* n2g  = (const float*)d_in[5];
    const float* n2b  = (const float*)d_in[6];
    const float* fc1w = (const float*)d_in[7];
    const float* fc1b = (const float*)d_in[8];
    const float* fc2w = (const float*)d_in[9];
    const float* fc2b = (const float*)d_in[10];
    float* out = (float*)d_out;

    // workspace layout (bytes)
    char* ws = (char*)d_ws;
    short* xn  = (short*)ws;                      // MM*512*2    = 102,760,448  (xn, then xn2)
    short* hb  = (short*)(ws + 102760448);        // MM*2048*2   = 411,041,792
    short* w1b = (short*)(ws + 513802240);        // 2048*512*2  =   2,097,152
    short* w2b = (short*)(ws + 515899392);        // 512*2048*2  =   2,097,152

    cvt_bf16<<<4096, 256, 0, stream>>>(fc1w, w1b, 2048 * 512);
    cvt_bf16<<<4096, 256, 0, stream>>>(fc2w, w2b, 512 * 2048);

    // LN1: x -> xn (bf16), 2 rows/block float4
    ln512v<<<MM / 2, 256, 0, stream>>>(x, n1g, n1b, xn);

    // spatial MLP + residual: x1 = x + y  (into d_out), 2ch/thread
    spatial_mlp<<<dim3(162, 16), 256, 0, stream>>>(xn, x, sw, sb, out);

    // LN2: x1 -> xn2 (bf16, reuse xn buffer)
    ln512v<<<MM / 2, 256, 0, stream>>>(out, n2g, n2b, xn);

    // FC1 + gelu -> h (bf16)   grid: 16 N-tiles x 784 M-tiles
    gemmrs<512, 2048, true><<<dim3(16, 784), 256, 0, stream>>>(xn, w1b, fc1b, nullptr, hb);

    // FC2 + bias + residual -> out (f32, reads x1 from d_out in place)
    gemmrs<2048, 512, false><<<dim3(4, 784), 256, 0, stream>>>(hb, w2b, fc2b, out, out);
}